// Round 2
// baseline (282.386 us; speedup 1.0000x reference)
//
#include <hip/hip_runtime.h>

#define BS 16
#define VL 1024
#define QL 64
#define DM 1024
#define MM (BS*VL)

typedef __attribute__((ext_vector_type(8))) short bf16x8;
typedef __attribute__((ext_vector_type(4))) float f32x4;

__device__ __forceinline__ unsigned short f2bf_rne(float f) {
  unsigned int u = __float_as_uint(f);
  u += 0x7fffu + ((u >> 16) & 1u);
  return (unsigned short)(u >> 16);
}
__device__ __forceinline__ void gl16(const void* g, void* l) {
  __builtin_amdgcn_global_load_lds(
      (const __attribute__((address_space(1))) unsigned int*)g,
      (__attribute__((address_space(3))) unsigned int*)l, 16, 0, 0);
}

// ---------------- sentence = weighted-pool of query; sn = ||sentence|| ----------
__global__ __launch_bounds__(256) void k_sentence(
    const float* __restrict__ query, const float* __restrict__ qmask,
    const float* __restrict__ pool_w, float* __restrict__ sentence,
    float* __restrict__ sn)
{
  int b = blockIdx.x, t = threadIdx.x;
  __shared__ float alpha[QL];
  __shared__ float red[4];
  const float* qb = query + (size_t)b*QL*DM;
  {
    int q = t >> 2, part = t & 3;                  // 4 threads per query row
    const float4* rp = (const float4*)(qb + q*DM + part*256);
    const float4* pp = (const float4*)(pool_w + part*256);
    float s = 0.f;
    for (int i = 0; i < 64; ++i) {
      float4 a = rp[i], w = pp[i];
      s += a.x*w.x + a.y*w.y + a.z*w.z + a.w*w.w;
    }
    s += __shfl_xor(s, 1);
    s += __shfl_xor(s, 2);
    if (part == 0) alpha[q] = s;
  }
  __syncthreads();
  if (t < 64) {                                    // softmax over q (one wave)
    float a = alpha[t] + (1.f - qmask[b*QL + t]) * (-1e30f);
    float m = a;
    for (int off = 32; off; off >>= 1) m = fmaxf(m, __shfl_xor(m, off));
    float e = expf(a - m);
    float ssum = e;
    for (int off = 32; off; off >>= 1) ssum += __shfl_xor(ssum, off);
    alpha[t] = e / ssum;
  }
  __syncthreads();
  float sq = 0.f;
  #pragma unroll
  for (int i = 0; i < 4; ++i) {
    int d = t + 256*i;
    float acc = 0.f;
    for (int q = 0; q < QL; ++q) acc += alpha[q] * qb[q*DM + d];
    sentence[(size_t)b*DM + d] = acc;
    sq += acc*acc;
  }
  for (int off = 32; off; off >>= 1) sq += __shfl_xor(sq, off);
  if ((t & 63) == 0) red[t >> 6] = sq;
  __syncthreads();
  if (t == 0) sn[b] = fmaxf(sqrtf(red[0]+red[1]+red[2]+red[3]), 1e-8f);
}

// ---- basev[b,:]=sentence[b]@W2 ; u_s=sim_w@W1 ; u_c=(cor_v*cor_q)@W3 -----------
// grid (8 kchunks, 4 nchunks); each W matrix read exactly once; atomic accumulate
__global__ __launch_bounds__(256) void k_gemvs(
    const float* __restrict__ mixer_w, const float* __restrict__ sentence,
    const float* __restrict__ sim_w, const float* __restrict__ cor_v_w,
    const float* __restrict__ cor_q_w, float* __restrict__ basev,
    float* __restrict__ u_s, float* __restrict__ u_c)
{
  int d0 = blockIdx.x * 128;
  int n0 = blockIdx.y * 256;
  int t = threadIdx.x;
  __shared__ float vec[18][128];
  for (int i = t; i < 18*128; i += 256) {
    int b = i >> 7, k = i & 127;
    float val;
    if (b < 16)      val = sentence[(size_t)b*DM + d0 + k];
    else if (b == 16) val = sim_w[d0 + k];
    else              val = cor_v_w[d0 + k] * cor_q_w[0];
    vec[b][k] = val;
  }
  __syncthreads();
  const float* W1 = mixer_w + (size_t)1*DM*DM + (size_t)d0*DM + n0 + t;
  const float* W2 = mixer_w + (size_t)2*DM*DM + (size_t)d0*DM + n0 + t;
  const float* W3 = mixer_w + (size_t)3*DM*DM + (size_t)d0*DM + n0 + t;
  float acc[16]; float a16 = 0.f, a17 = 0.f;
  #pragma unroll
  for (int b = 0; b < 16; ++b) acc[b] = 0.f;
  for (int k = 0; k < 128; ++k) {
    float w1 = W1[(size_t)k*DM], w2 = W2[(size_t)k*DM], w3 = W3[(size_t)k*DM];
    #pragma unroll
    for (int b = 0; b < 16; ++b) acc[b] += vec[b][k] * w2;
    a16 += vec[16][k] * w1;
    a17 += vec[17][k] * w3;
  }
  #pragma unroll
  for (int b = 0; b < 16; ++b) atomicAdd(&basev[(size_t)b*DM + n0 + t], acc[b]);
  atomicAdd(&u_s[n0 + t], a16);
  atomicAdd(&u_c[n0 + t], a17);
}

// ---- video f32 -> bf16 A, fused full-row dot/normsq -> simv --------------------
// one wave per row: 64 lanes x 4 float4 = 1024 elems
__global__ __launch_bounds__(256) void k_convA(
    const float* __restrict__ video, const float* __restrict__ sentence,
    const float* __restrict__ sn, const float* __restrict__ vmask,
    unsigned short* __restrict__ Ahi, float* __restrict__ simv)
{
  int wave = threadIdx.x >> 6, lane = threadIdx.x & 63;
  int row = blockIdx.x * 4 + wave;
  int b = row >> 10;
  const float4* vp = (const float4*)(video + (size_t)row*DM);
  const float4* sp = (const float4*)(sentence + (size_t)b*DM);
  float dot = 0.f, sq = 0.f;
  #pragma unroll
  for (int i = 0; i < 4; ++i) {
    float4 v = vp[lane + 64*i];
    float4 s = sp[lane + 64*i];
    dot += v.x*s.x + v.y*s.y + v.z*s.z + v.w*s.w;
    sq  += v.x*v.x + v.y*v.y + v.z*v.z + v.w*v.w;
    ushort4 h;
    h.x = f2bf_rne(v.x); h.y = f2bf_rne(v.y);
    h.z = f2bf_rne(v.z); h.w = f2bf_rne(v.w);
    *(ushort4*)(Ahi + (size_t)row*DM + (lane + 64*i)*4) = h;
  }
  #pragma unroll
  for (int off = 32; off; off >>= 1) {
    dot += __shfl_xor(dot, off);
    sq  += __shfl_xor(sq,  off);
  }
  if (lane == 0) {
    float vn = fmaxf(sqrtf(sq), 1e-8f);
    simv[row] = dot / (vn * sn[b]) + logf(vmask[row] + 1e-45f);
  }
}

// ---- W_v f32 -> transposed B^T [n][k] bf16 -------------------------------------
__global__ __launch_bounds__(256) void k_convB(
    const float* __restrict__ Wv, unsigned short* __restrict__ Bhi)
{
  __shared__ float tile[64][65];
  int bk = (blockIdx.x & 15) * 64;
  int bn = (blockIdx.x >> 4) * 64;
  int t = threadIdx.x;
  int kr = t >> 2, nc = (t & 3) * 16;
  const float4* src = (const float4*)(Wv + (size_t)(bk + kr)*DM + bn + nc);
  #pragma unroll
  for (int i = 0; i < 4; ++i) {
    float4 v = src[i];
    tile[kr][nc + i*4 + 0] = v.x;
    tile[kr][nc + i*4 + 1] = v.y;
    tile[kr][nc + i*4 + 2] = v.z;
    tile[kr][nc + i*4 + 3] = v.w;
  }
  __syncthreads();
  int n = t >> 2, kc = (t & 3) * 16;
  #pragma unroll
  for (int i = 0; i < 16; i += 4) {
    ushort4 h;
    h.x = f2bf_rne(tile[kc+i+0][n]);
    h.y = f2bf_rne(tile[kc+i+1][n]);
    h.z = f2bf_rne(tile[kc+i+2][n]);
    h.w = f2bf_rne(tile[kc+i+3][n]);
    *(ushort4*)(Bhi + (size_t)(bn+n)*DM + bk + kc + i) = h;
  }
}

// ---- main GEMM: out = relu(video@W_v + sim*u_s + u_c + base + bias) ------------
// plain bf16, 128x128 tile, 4 waves (2x2 of 64x64), 16x16x32 MFMA, gl_lds w=16
__global__ __launch_bounds__(256) void k_gemm(
    const unsigned short* __restrict__ Ahi, const unsigned short* __restrict__ Bhi,
    const float* __restrict__ simv, const float* __restrict__ u_s,
    const float* __restrict__ u_c, const float* __restrict__ basev,
    const float* __restrict__ mixer_b, float* __restrict__ out)
{
  __shared__ __align__(16) unsigned short At[128][32];
  __shared__ __align__(16) unsigned short Bt[128][32];

  int bid = blockIdx.x;
  // bijective XCD swizzle (nwg=1024, 1024%8==0)
  int swz = (bid & 7) * 128 + (bid >> 3);
  int bm = swz >> 3;          // 0..127
  int bn = swz & 7;           // 0..7

  int t = threadIdx.x;
  int wave = t >> 6;
  int lane = t & 63;
  int wm = (wave >> 1) * 64;
  int wn = (wave & 1) * 64;
  int lr = lane & 15;
  int lk = (lane >> 4) * 8;

  f32x4 acc[4][4];
  #pragma unroll
  for (int i = 0; i < 4; ++i)
    #pragma unroll
    for (int j = 0; j < 4; ++j) acc[i][j] = (f32x4){0.f, 0.f, 0.f, 0.f};

  int srow  = t >> 2;         // staging row within 64-row half
  int skoff = (t & 3) * 8;    // staging k offset (elems)

  char* ldsA0 = (char*)At + wave*1024;
  char* ldsA1 = (char*)At + 4096 + wave*1024;
  char* ldsB0 = (char*)Bt + wave*1024;
  char* ldsB1 = (char*)Bt + 4096 + wave*1024;

  const unsigned short* Ap = Ahi + (size_t)(bm*128 + srow)*DM + skoff;
  const unsigned short* Bp = Bhi + (size_t)(bn*128 + srow)*DM + skoff;

  #pragma unroll 1
  for (int ks = 0; ks < DM; ks += 32) {
    gl16(Ap + ks,          ldsA0);
    gl16(Ap + ks + 64*DM,  ldsA1);
    gl16(Bp + ks,          ldsB0);
    gl16(Bp + ks + 64*DM,  ldsB1);
    __syncthreads();
    bf16x8 af[4], bfr[4];
    #pragma unroll
    for (int mi = 0; mi < 4; ++mi)
      af[mi] = *(const bf16x8*)&At[wm + mi*16 + lr][lk];
    #pragma unroll
    for (int nj = 0; nj < 4; ++nj)
      bfr[nj] = *(const bf16x8*)&Bt[wn + nj*16 + lr][lk];
    #pragma unroll
    for (int mi = 0; mi < 4; ++mi)
      #pragma unroll
      for (int nj = 0; nj < 4; ++nj)
        acc[mi][nj] = __builtin_amdgcn_mfma_f32_16x16x32_bf16(
            af[mi], bfr[nj], acc[mi][nj], 0, 0, 0);
    __syncthreads();
  }

  // epilogue: C/D layout col=lane&15, row=(lane>>4)*4+reg  [m89]
  int orow0 = bm*128 + wm;
  int ocol0 = bn*128 + wn;
  const float* bb = basev + (size_t)((bm*128) >> 10)*DM;   // batch uniform per block
  float usv[4], cv[4];
  #pragma unroll
  for (int nj = 0; nj < 4; ++nj) {
    int col = ocol0 + nj*16 + lr;
    usv[nj] = u_s[col];
    cv[nj]  = bb[col] + u_c[col] + mixer_b[col];
  }
  int rbase = (lane >> 4) * 4;
  #pragma unroll
  for (int mi = 0; mi < 4; ++mi) {
    #pragma unroll
    for (int r = 0; r < 4; ++r) {
      int row = orow0 + mi*16 + rbase + r;
      float sim = simv[row];
      #pragma unroll
      for (int nj = 0; nj < 4; ++nj) {
        float v = acc[mi][nj][r] + sim*usv[nj] + cv[nj];
        out[(size_t)row*DM + ocol0 + nj*16 + lr] = fmaxf(v, 0.f);
      }
    }
  }
}

extern "C" void kernel_launch(void* const* d_in, const int* in_sizes, int n_in,
                              void* d_out, int out_size, void* d_ws, size_t ws_size,
                              hipStream_t stream) {
  const float* video   = (const float*)d_in[0];
  const float* query   = (const float*)d_in[1];
  const float* vmask   = (const float*)d_in[2];
  const float* qmask   = (const float*)d_in[3];
  const float* sim_w   = (const float*)d_in[4];
  const float* cor_v_w = (const float*)d_in[5];
  const float* cor_q_w = (const float*)d_in[6];
  const float* pool_w  = (const float*)d_in[7];
  const float* mixer_w = (const float*)d_in[8];
  const float* mixer_b = (const float*)d_in[9];
  float* out = (float*)d_out;

  float* fws      = (float*)d_ws;
  float* sentence = fws;                    // 16384
  float* sn       = sentence + 16384;       // 64 (padded)
  float* u_s      = sn + 64;                // 1024
  float* u_c      = u_s + 1024;             // 1024
  float* basev    = u_c + 1024;             // 16384
  float* simv     = basev + 16384;          // 16384
  unsigned short* Ahi = (unsigned short*)(simv + 16384);   // 16M elems (32MB)
  unsigned short* Bhi = Ahi + (size_t)MM*DM;               // 1M elems (2MB)

  // zero the atomic-accumulated region [u_s | u_c | basev]
  hipMemsetAsync(u_s, 0, (1024 + 1024 + 16384) * sizeof(float), stream);

  k_sentence<<<dim3(16), dim3(256), 0, stream>>>(query, qmask, pool_w, sentence, sn);
  k_gemvs<<<dim3(8, 4), dim3(256), 0, stream>>>(mixer_w, sentence, sim_w,
                                                cor_v_w, cor_q_w, basev, u_s, u_c);
  k_convA<<<dim3(4096), dim3(256), 0, stream>>>(video, sentence, sn, vmask, Ahi, simv);
  k_convB<<<dim3(256), dim3(256), 0, stream>>>(mixer_w, Bhi);
  k_gemm<<<dim3(1024), dim3(256), 0, stream>>>(Ahi, Bhi, simv, u_s, u_c,
                                               basev, mixer_b, out);
}

// Round 3
// 220.693 us; speedup vs baseline: 1.2795x; 1.2795x over previous
//
#include <hip/hip_runtime.h>

#define BS 16
#define VL 1024
#define QL 64
#define DM 1024
#define MM (BS*VL)

typedef __attribute__((ext_vector_type(8))) short bf16x8;
typedef __attribute__((ext_vector_type(4))) float f32x4;

__device__ __forceinline__ unsigned short f2bf_rne(float f) {
  unsigned int u = __float_as_uint(f);
  u += 0x7fffu + ((u >> 16) & 1u);
  return (unsigned short)(u >> 16);
}
__device__ __forceinline__ void gl16(const void* g, void* l) {
  __builtin_amdgcn_global_load_lds(
      (const __attribute__((address_space(1))) unsigned int*)g,
      (__attribute__((address_space(3))) unsigned int*)l, 16, 0, 0);
}

// ---------------- sentence = weighted-pool of query; sn = ||sentence|| ----------
__global__ __launch_bounds__(256) void k_sentence(
    const float* __restrict__ query, const float* __restrict__ qmask,
    const float* __restrict__ pool_w, float* __restrict__ sentence,
    float* __restrict__ sn)
{
  int b = blockIdx.x, t = threadIdx.x;
  __shared__ float alpha[QL];
  __shared__ float red[4];
  const float* qb = query + (size_t)b*QL*DM;
  {
    int q = t >> 2, part = t & 3;                  // 4 threads per query row
    const float4* rp = (const float4*)(qb + q*DM + part*256);
    const float4* pp = (const float4*)(pool_w + part*256);
    float s = 0.f;
    for (int i = 0; i < 64; ++i) {
      float4 a = rp[i], w = pp[i];
      s += a.x*w.x + a.y*w.y + a.z*w.z + a.w*w.w;
    }
    s += __shfl_xor(s, 1);
    s += __shfl_xor(s, 2);
    if (part == 0) alpha[q] = s;
  }
  __syncthreads();
  if (t < 64) {                                    // softmax over q (one wave)
    float a = alpha[t] + (1.f - qmask[b*QL + t]) * (-1e30f);
    float m = a;
    for (int off = 32; off; off >>= 1) m = fmaxf(m, __shfl_xor(m, off));
    float e = expf(a - m);
    float ssum = e;
    for (int off = 32; off; off >>= 1) ssum += __shfl_xor(ssum, off);
    alpha[t] = e / ssum;
  }
  __syncthreads();
  float sq = 0.f;
  #pragma unroll
  for (int i = 0; i < 4; ++i) {
    int d = t + 256*i;
    float acc = 0.f;
    for (int q = 0; q < QL; ++q) acc += alpha[q] * qb[q*DM + d];
    sentence[(size_t)b*DM + d] = acc;
    sq += acc*acc;
  }
  for (int off = 32; off; off >>= 1) sq += __shfl_xor(sq, off);
  if ((t & 63) == 0) red[t >> 6] = sq;
  __syncthreads();
  if (t == 0) sn[b] = fmaxf(sqrtf(red[0]+red[1]+red[2]+red[3]), 1e-8f);
}

// ---- GEMVs: partial[kchunk][18][1024]; 256 blocks, no atomics ------------------
// rows 0..15: sentence[b]@W2 ; 16: sim_w@W1 ; 17: (cor_v*cor_q)@W3
__global__ __launch_bounds__(256) void k_gemvs(
    const float* __restrict__ mixer_w, const float* __restrict__ sentence,
    const float* __restrict__ sim_w, const float* __restrict__ cor_v_w,
    const float* __restrict__ cor_q_w, float* __restrict__ partial)
{
  int d0 = blockIdx.x * 32;    // 32 k-chunks
  int n0 = blockIdx.y * 128;   // 8 n-chunks
  int t = threadIdx.x;
  int col = t & 127, kh = t >> 7;    // two 16-deep k-halves
  __shared__ float vec[18][32];
  __shared__ float red[2][18][128];
  for (int i = t; i < 18*32; i += 256) {
    int b = i >> 5, k = i & 31;
    float val;
    if (b < 16)       val = sentence[(size_t)b*DM + d0 + k];
    else if (b == 16) val = sim_w[d0 + k];
    else              val = cor_v_w[d0 + k] * cor_q_w[0];
    vec[b][k] = val;
  }
  __syncthreads();
  float acc[18];
  #pragma unroll
  for (int j = 0; j < 18; ++j) acc[j] = 0.f;
  const float* Wb = mixer_w + (size_t)(d0 + kh*16)*DM + n0 + col;  // inside W0; W1/2/3 at +i*DM*DM
  #pragma unroll 1
  for (int k = 0; k < 16; ++k) {
    const float* wr = Wb + (size_t)k*DM;
    float w1 = wr[(size_t)1*DM*DM];
    float w2 = wr[(size_t)2*DM*DM];
    float w3 = wr[(size_t)3*DM*DM];
    int kk = kh*16 + k;
    #pragma unroll
    for (int b = 0; b < 16; ++b) acc[b] += vec[b][kk] * w2;
    acc[16] += vec[16][kk] * w1;
    acc[17] += vec[17][kk] * w3;
  }
  #pragma unroll
  for (int j = 0; j < 18; ++j) red[kh][j][col] = acc[j];
  __syncthreads();
  #pragma unroll
  for (int r = 0; r < 9; ++r) {                    // 2304 outputs / 256 threads
    int idx = t + 256*r;
    int j = idx >> 7, c2 = idx & 127;
    partial[((size_t)blockIdx.x*18 + j)*1024 + n0 + c2] = red[0][j][c2] + red[1][j][c2];
  }
}

__global__ __launch_bounds__(256) void k_reduce(
    const float* __restrict__ partial, float* __restrict__ basev,
    float* __restrict__ u_s, float* __restrict__ u_c)
{
  int idx = blockIdx.x * 256 + threadIdx.x;        // 0..18431
  int j = idx >> 10, col = idx & 1023;
  float s = 0.f;
  #pragma unroll 4
  for (int b = 0; b < 32; ++b) s += partial[((size_t)b*18 + j)*1024 + col];
  if (j < 16)       basev[(size_t)j*1024 + col] = s;
  else if (j == 16) u_s[col] = s;
  else              u_c[col] = s;
}

// ---- fused: blocks <4096: video f32 -> bf16 A + sim ; blocks >=4096: W_v -> B^T -
__global__ __launch_bounds__(256) void k_conv(
    const float* __restrict__ video, const float* __restrict__ sentence,
    const float* __restrict__ sn, const float* __restrict__ vmask,
    const float* __restrict__ Wv,
    unsigned short* __restrict__ Ahi, unsigned short* __restrict__ Bhi,
    float* __restrict__ simv)
{
  __shared__ float tile[64][65];
  int t = threadIdx.x;
  if (blockIdx.x < 4096) {
    int wave = t >> 6, lane = t & 63;
    int row = blockIdx.x * 4 + wave;
    int b = row >> 10;
    const float4* vp = (const float4*)(video + (size_t)row*DM);
    const float4* sp = (const float4*)(sentence + (size_t)b*DM);
    float dot = 0.f, sq = 0.f;
    #pragma unroll
    for (int i = 0; i < 4; ++i) {
      float4 v = vp[lane + 64*i];
      float4 s = sp[lane + 64*i];
      dot += v.x*s.x + v.y*s.y + v.z*s.z + v.w*s.w;
      sq  += v.x*v.x + v.y*v.y + v.z*v.z + v.w*v.w;
      ushort4 h;
      h.x = f2bf_rne(v.x); h.y = f2bf_rne(v.y);
      h.z = f2bf_rne(v.z); h.w = f2bf_rne(v.w);
      *(ushort4*)(Ahi + (size_t)row*DM + (lane + 64*i)*4) = h;
    }
    #pragma unroll
    for (int off = 32; off; off >>= 1) {
      dot += __shfl_xor(dot, off);
      sq  += __shfl_xor(sq,  off);
    }
    if (lane == 0) {
      float vn = fmaxf(sqrtf(sq), 1e-8f);
      simv[row] = dot / (vn * sn[b]) + logf(vmask[row] + 1e-45f);
    }
  } else {
    int bb = blockIdx.x - 4096;
    int bk = (bb & 15) * 64;
    int bn = (bb >> 4) * 64;
    int kr = t >> 2, nc = (t & 3) * 16;
    const float4* src = (const float4*)(Wv + (size_t)(bk + kr)*DM + bn + nc);
    #pragma unroll
    for (int i = 0; i < 4; ++i) {
      float4 v = src[i];
      tile[kr][nc + i*4 + 0] = v.x;
      tile[kr][nc + i*4 + 1] = v.y;
      tile[kr][nc + i*4 + 2] = v.z;
      tile[kr][nc + i*4 + 3] = v.w;
    }
    __syncthreads();
    int n = t >> 2, kc = (t & 3) * 16;
    #pragma unroll
    for (int i = 0; i < 16; i += 4) {
      ushort4 h;
      h.x = f2bf_rne(tile[kc+i+0][n]);
      h.y = f2bf_rne(tile[kc+i+1][n]);
      h.z = f2bf_rne(tile[kc+i+2][n]);
      h.w = f2bf_rne(tile[kc+i+3][n]);
      *(ushort4*)(Bhi + (size_t)(bn+n)*DM + bk + kc + i) = h;
    }
  }
}

// ---- main GEMM: out = relu(video@W_v + sim*u_s + u_c + base + bias) ------------
// 128x128 tile, BK=64, 2-phase LDS double-buffer, XOR-swizzled LDS image
// (swizzle applied on global SOURCE of global_load_lds; LDS dest stays linear;
//  ds_read applies the same XOR -> conflict-free: banks 4*(g ^ (lr&7)))
__global__ __launch_bounds__(256) void k_gemm(
    const unsigned short* __restrict__ Ahi, const unsigned short* __restrict__ Bhi,
    const float* __restrict__ simv, const float* __restrict__ u_s,
    const float* __restrict__ u_c, const float* __restrict__ basev,
    const float* __restrict__ mixer_b, float* __restrict__ out)
{
  __shared__ __align__(16) unsigned short At[2][128][64];   // 32 KB
  __shared__ __align__(16) unsigned short Bt[2][128][64];   // 32 KB

  int bid = blockIdx.x;
  // bijective XCD swizzle (nwg=1024, 1024%8==0)
  int swz = (bid & 7) * 128 + (bid >> 3);
  int bm = swz >> 3;          // 0..127
  int bn = swz & 7;           // 0..7

  int t = threadIdx.x;
  int wave = t >> 6, lane = t & 63;
  int wm = (wave >> 1) * 64, wn = (wave & 1) * 64;
  int lr = lane & 15, g = lane >> 4;
  int rx = 8 * (lr & 7);      // read-side XOR (elems; rows mod 8)

  f32x4 acc[4][4];
  #pragma unroll
  for (int i = 0; i < 4; ++i)
    #pragma unroll
    for (int j = 0; j < 4; ++j) acc[i][j] = (f32x4){0.f, 0.f, 0.f, 0.f};

  // staging: image[row][col'] with col' = col ^ (8*(row&7)); LDS write is linear,
  // so gather from source col = 8*((chunk j) ^ (row&7)).
  int srow = t >> 3;                       // 0..31 (+32q)
  int scol = 8 * ((t & 7) ^ (srow & 7));   // row&7 invariant under +32q
  const unsigned short* Ap = Ahi + (size_t)(bm*128 + srow)*DM + scol;
  const unsigned short* Bp = Bhi + (size_t)(bn*128 + srow)*DM + scol;
  char* ldsA = (char*)&At[0][0][0] + wave*1024;
  char* ldsB = (char*)&Bt[0][0][0] + wave*1024;

  #define STAGE(kt, buf) do {                                         \
    const unsigned short* _a = Ap + (kt)*64;                          \
    const unsigned short* _b = Bp + (kt)*64;                          \
    _Pragma("unroll")                                                 \
    for (int q = 0; q < 4; ++q) {                                     \
      gl16(_a + (size_t)q*32*DM, ldsA + (buf)*16384 + q*4096);        \
      gl16(_b + (size_t)q*32*DM, ldsB + (buf)*16384 + q*4096);        \
    }                                                                 \
  } while (0)

  STAGE(0, 0);
  __syncthreads();

  #pragma unroll 1
  for (int kt = 0; kt < 16; ++kt) {
    int buf = kt & 1;
    if (kt < 15) STAGE(kt + 1, buf ^ 1);   // issue loads first: overlap w/ compute
    const unsigned short* Ab = &At[buf][0][0];
    const unsigned short* Bb = &Bt[buf][0][0];
    #pragma unroll
    for (int s = 0; s < 2; ++s) {
      int cb = (s*32 + 8*g) ^ rx;          // swizzled column of this frag
      bf16x8 af[4], bfr[4];
      #pragma unroll
      for (int mi = 0; mi < 4; ++mi)
        af[mi] = *(const bf16x8*)(Ab + (wm + mi*16 + lr)*64 + cb);
      #pragma unroll
      for (int nj = 0; nj < 4; ++nj)
        bfr[nj] = *(const bf16x8*)(Bb + (wn + nj*16 + lr)*64 + cb);
      #pragma unroll
      for (int mi = 0; mi < 4; ++mi)
        #pragma unroll
        for (int nj = 0; nj < 4; ++nj)
          acc[mi][nj] = __builtin_amdgcn_mfma_f32_16x16x32_bf16(
              af[mi], bfr[nj], acc[mi][nj], 0, 0, 0);
    }
    __syncthreads();   // drains vmcnt: next buf staged; cur buf free for reuse
  }

  // epilogue: C/D layout col=lane&15, row=(lane>>4)*4+reg  [m89]
  int orow0 = bm*128 + wm;
  int ocol0 = bn*128 + wn;
  const float* bb = basev + (size_t)((bm*128) >> 10)*DM;   // batch uniform per block
  float usv[4], cv[4];
  #pragma unroll
  for (int nj = 0; nj < 4; ++nj) {
    int col = ocol0 + nj*16 + lr;
    usv[nj] = u_s[col];
    cv[nj]  = bb[col] + u_c[col] + mixer_b[col];
  }
  int rbase = g * 4;
  #pragma unroll
  for (int mi = 0; mi < 4; ++mi) {
    #pragma unroll
    for (int r = 0; r < 4; ++r) {
      int row = orow0 + mi*16 + rbase + r;
      float sim = simv[row];
      #pragma unroll
      for (int nj = 0; nj < 4; ++nj) {
        float v = acc[mi][nj][r] + sim*usv[nj] + cv[nj];
        out[(size_t)row*DM + ocol0 + nj*16 + lr] = fmaxf(v, 0.f);
      }
    }
  }
  #undef STAGE
}

extern "C" void kernel_launch(void* const* d_in, const int* in_sizes, int n_in,
                              void* d_out, int out_size, void* d_ws, size_t ws_size,
                              hipStream_t stream) {
  const float* video   = (const float*)d_in[0];
  const float* query   = (const float*)d_in[1];
  const float* vmask   = (const float*)d_in[2];
  const float* qmask   = (const float*)d_in[3];
  const float* sim_w   = (const float*)d_in[4];
  const float* cor_v_w = (const float*)d_in[5];
  const float* cor_q_w = (const float*)d_in[6];
  const float* pool_w  = (const float*)d_in[7];
  const float* mixer_w = (const float*)d_in[8];
  const float* mixer_b = (const float*)d_in[9];
  float* out = (float*)d_out;

  float* fws      = (float*)d_ws;
  float* sentence = fws;                    // 16384
  float* sn       = sentence + 16384;       // 64 (padded)
  float* u_s      = sn + 64;                // 1024
  float* u_c      = u_s + 1024;             // 1024
  float* basev    = u_c + 1024;             // 16384
  float* simv     = basev + 16384;          // 16384
  float* partial  = simv + 16384;           // 32*18*1024 = 589824
  unsigned short* Ahi = (unsigned short*)(partial + 589824);  // 16M elems (32MB)
  unsigned short* Bhi = Ahi + (size_t)MM*DM;                  // 1M elems (2MB)

  k_sentence<<<dim3(16), dim3(256), 0, stream>>>(query, qmask, pool_w, sentence, sn);
  k_conv<<<dim3(4352), dim3(256), 0, stream>>>(video, sentence, sn, vmask,
                                               mixer_w, Ahi, Bhi, simv);
  k_gemvs<<<dim3(32, 8), dim3(256), 0, stream>>>(mixer_w, sentence, sim_w,
                                                 cor_v_w, cor_q_w, partial);
  k_reduce<<<dim3(72), dim3(256), 0, stream>>>(partial, basev, u_s, u_c);
  k_gemm<<<dim3(1024), dim3(256), 0, stream>>>(Ahi, Bhi, simv, u_s, u_c,
                                               basev, mixer_b, out);
}

// Round 4
// 219.369 us; speedup vs baseline: 1.2873x; 1.0060x over previous
//
#include <hip/hip_runtime.h>

#define BS 16
#define VL 1024
#define QL 64
#define DM 1024
#define MM (BS*VL)

typedef __attribute__((ext_vector_type(8))) short bf16x8;
typedef __attribute__((ext_vector_type(4))) float f32x4;

__device__ __forceinline__ unsigned short f2bf_rne(float f) {
  unsigned int u = __float_as_uint(f);
  u += 0x7fffu + ((u >> 16) & 1u);
  return (unsigned short)(u >> 16);
}
__device__ __forceinline__ void gl16(const void* g, void* l) {
  __builtin_amdgcn_global_load_lds(
      (const __attribute__((address_space(1))) unsigned int*)g,
      (__attribute__((address_space(3))) unsigned int*)l, 16, 0, 0);
}

// ---- k_alpha: alpha_raw[b*64+q] = query[b,q,:]·pool_w  (256 blocks, 4 waves) --
__global__ __launch_bounds__(256) void k_alpha(
    const float* __restrict__ query, const float* __restrict__ pool_w,
    float* __restrict__ alpha_raw)
{
  int wave = threadIdx.x >> 6, lane = threadIdx.x & 63;
  int q = blockIdx.x * 4 + wave;                 // 0..1023
  const float4* rp = (const float4*)(query + (size_t)q*DM);
  const float4* pp = (const float4*)pool_w;
  float s = 0.f;
  #pragma unroll
  for (int i = 0; i < 4; ++i) {
    float4 a = rp[lane + 64*i], w = pp[lane + 64*i];
    s += a.x*w.x + a.y*w.y + a.z*w.z + a.w*w.w;
  }
  #pragma unroll
  for (int off = 32; off; off >>= 1) s += __shfl_xor(s, off);
  if (lane == 0) alpha_raw[q] = s;
}

// ---- k_sentence2: block (b, dchunk): softmax(alpha) redundant, weighted pool --
// writes sentence[b, dc*128..+127] and psq[b*8+dc] (partial sum of squares)
__global__ __launch_bounds__(256) void k_sentence2(
    const float* __restrict__ query, const float* __restrict__ qmask,
    const float* __restrict__ alpha_raw, float* __restrict__ sentence,
    float* __restrict__ psq)
{
  int b = blockIdx.x, dc = blockIdx.y;
  int t = threadIdx.x;
  __shared__ float al[QL];
  __shared__ float red2[2][128];
  __shared__ float sqred[2];
  if (t < 64) {
    float a = alpha_raw[b*QL + t] + (1.f - qmask[b*QL + t]) * (-1e30f);
    float m = a;
    #pragma unroll
    for (int off = 32; off; off >>= 1) m = fmaxf(m, __shfl_xor(m, off));
    float e = expf(a - m);
    float s = e;
    #pragma unroll
    for (int off = 32; off; off >>= 1) s += __shfl_xor(s, off);
    al[t] = e / s;
  }
  __syncthreads();
  int col = t & 127, half = t >> 7;
  const float* qb = query + (size_t)b*QL*DM + dc*128 + col;
  float acc = 0.f;
  for (int q = half*32; q < half*32 + 32; ++q)
    acc += al[q] * qb[(size_t)q*DM];
  red2[half][col] = acc;
  __syncthreads();
  if (t < 128) {
    float s = red2[0][t] + red2[1][t];
    sentence[(size_t)b*DM + dc*128 + t] = s;
    float sq = s*s;
    #pragma unroll
    for (int off = 32; off; off >>= 1) sq += __shfl_xor(sq, off);
    if ((t & 63) == 0) sqred[t >> 6] = sq;
  }
  __syncthreads();
  if (t == 0) psq[b*8 + dc] = sqred[0] + sqred[1];
}

// ---- GEMVs: partial[kchunk][18][1024]; 256 blocks, no atomics ------------------
__global__ __launch_bounds__(256) void k_gemvs(
    const float* __restrict__ mixer_w, const float* __restrict__ sentence,
    const float* __restrict__ sim_w, const float* __restrict__ cor_v_w,
    const float* __restrict__ cor_q_w, float* __restrict__ partial)
{
  int d0 = blockIdx.x * 32;
  int n0 = blockIdx.y * 128;
  int t = threadIdx.x;
  int col = t & 127, kh = t >> 7;
  __shared__ float vec[18][32];
  __shared__ float red[2][18][128];
  for (int i = t; i < 18*32; i += 256) {
    int b = i >> 5, k = i & 31;
    float val;
    if (b < 16)       val = sentence[(size_t)b*DM + d0 + k];
    else if (b == 16) val = sim_w[d0 + k];
    else              val = cor_v_w[d0 + k] * cor_q_w[0];
    vec[b][k] = val;
  }
  __syncthreads();
  float acc[18];
  #pragma unroll
  for (int j = 0; j < 18; ++j) acc[j] = 0.f;
  const float* Wb = mixer_w + (size_t)(d0 + kh*16)*DM + n0 + col;
  #pragma unroll 1
  for (int k = 0; k < 16; ++k) {
    const float* wr = Wb + (size_t)k*DM;
    float w1 = wr[(size_t)1*DM*DM];
    float w2 = wr[(size_t)2*DM*DM];
    float w3 = wr[(size_t)3*DM*DM];
    int kk = kh*16 + k;
    #pragma unroll
    for (int b = 0; b < 16; ++b) acc[b] += vec[b][kk] * w2;
    acc[16] += vec[16][kk] * w1;
    acc[17] += vec[17][kk] * w3;
  }
  #pragma unroll
  for (int j = 0; j < 18; ++j) red[kh][j][col] = acc[j];
  __syncthreads();
  #pragma unroll
  for (int r = 0; r < 9; ++r) {
    int idx = t + 256*r;
    int j = idx >> 7, c2 = idx & 127;
    partial[((size_t)blockIdx.x*18 + j)*1024 + n0 + c2] = red[0][j][c2] + red[1][j][c2];
  }
}

__global__ __launch_bounds__(256) void k_reduce(
    const float* __restrict__ partial, float* __restrict__ basev,
    float* __restrict__ u_s, float* __restrict__ u_c)
{
  int idx = blockIdx.x * 256 + threadIdx.x;
  int j = idx >> 10, col = idx & 1023;
  float s = 0.f;
  #pragma unroll 4
  for (int b = 0; b < 32; ++b) s += partial[((size_t)b*18 + j)*1024 + col];
  if (j < 16)       basev[(size_t)j*1024 + col] = s;
  else if (j == 16) u_s[col] = s;
  else              u_c[col] = s;
}

// ---- fused: blocks <4096: video -> bf16 A + sim ; >=4096: W_v -> B^T -----------
__global__ __launch_bounds__(256) void k_conv(
    const float* __restrict__ video, const float* __restrict__ sentence,
    const float* __restrict__ psq, const float* __restrict__ vmask,
    const float* __restrict__ Wv,
    unsigned short* __restrict__ Ahi, unsigned short* __restrict__ Bhi,
    float* __restrict__ simv)
{
  __shared__ float tile[64][65];
  int t = threadIdx.x;
  if (blockIdx.x < 4096) {
    int wave = t >> 6, lane = t & 63;
    int row = blockIdx.x * 4 + wave;
    int b = row >> 10;
    const float4* vp = (const float4*)(video + (size_t)row*DM);
    const float4* sp = (const float4*)(sentence + (size_t)b*DM);
    float dot = 0.f, sq = 0.f;
    #pragma unroll
    for (int i = 0; i < 4; ++i) {
      float4 v = vp[lane + 64*i];
      float4 s = sp[lane + 64*i];
      dot += v.x*s.x + v.y*s.y + v.z*s.z + v.w*s.w;
      sq  += v.x*v.x + v.y*v.y + v.z*v.z + v.w*v.w;
      ushort4 h;
      h.x = f2bf_rne(v.x); h.y = f2bf_rne(v.y);
      h.z = f2bf_rne(v.z); h.w = f2bf_rne(v.w);
      *(ushort4*)(Ahi + (size_t)row*DM + (lane + 64*i)*4) = h;
    }
    #pragma unroll
    for (int off = 32; off; off >>= 1) {
      dot += __shfl_xor(dot, off);
      sq  += __shfl_xor(sq,  off);
    }
    if (lane == 0) {
      float ss = 0.f;
      #pragma unroll
      for (int i = 0; i < 8; ++i) ss += psq[b*8 + i];
      float snv = fmaxf(sqrtf(ss), 1e-8f);
      float vn  = fmaxf(sqrtf(sq), 1e-8f);
      simv[row] = dot / (vn * snv) + logf(vmask[row] + 1e-45f);
    }
  } else {
    int bb = blockIdx.x - 4096;
    int bk = (bb & 15) * 64;
    int bn = (bb >> 4) * 64;
    int kr = t >> 2, nc = (t & 3) * 16;
    const float4* src = (const float4*)(Wv + (size_t)(bk + kr)*DM + bn + nc);
    #pragma unroll
    for (int i = 0; i < 4; ++i) {
      float4 v = src[i];
      tile[kr][nc + i*4 + 0] = v.x;
      tile[kr][nc + i*4 + 1] = v.y;
      tile[kr][nc + i*4 + 2] = v.z;
      tile[kr][nc + i*4 + 3] = v.w;
    }
    __syncthreads();
    int n = t >> 2, kc = (t & 3) * 16;
    #pragma unroll
    for (int i = 0; i < 16; i += 4) {
      ushort4 h;
      h.x = f2bf_rne(tile[kc+i+0][n]);
      h.y = f2bf_rne(tile[kc+i+1][n]);
      h.z = f2bf_rne(tile[kc+i+2][n]);
      h.w = f2bf_rne(tile[kc+i+3][n]);
      *(ushort4*)(Bhi + (size_t)(bn+n)*DM + bk + kc + i) = h;
    }
  }
}

// ---- main GEMM: 256x256 tile, 8 waves, BK=64, 4-phase interleave + counted vmcnt
// out = relu(video@W_v + sim*u_s + u_c + base + bias)
// Each wave stages exactly the A-half/B-quarter it consumes (8x 1KB gl_lds/tile).
// Swizzle: LDS[r][c'] = src[r][c' ^ 8*(r&7)]; reads XOR the same -> conflict-free.
__global__ __launch_bounds__(512, 2) void k_gemm(
    const unsigned short* __restrict__ Ahi, const unsigned short* __restrict__ Bhi,
    const float* __restrict__ simv, const float* __restrict__ u_s,
    const float* __restrict__ u_c, const float* __restrict__ basev,
    const float* __restrict__ mixer_b, float* __restrict__ out)
{
  __shared__ __align__(16) unsigned short A_lds[2][256][64];   // 64 KB
  __shared__ __align__(16) unsigned short B_lds[2][256][64];   // 64 KB

  int bid = blockIdx.x;
  int swz = (bid & 7) * 32 + (bid >> 3);     // 256 blocks, bijective XCD swizzle
  int bm = swz >> 2;                         // 0..63
  int bn = swz & 3;                          // 0..3

  int t = threadIdx.x;
  int w = t >> 6, lane = t & 63;
  int wmh = w >> 2;        // A-half (0,1): rows wmh*128..+127
  int wq  = w & 3;         // B-quarter:   rows wq*64..+63
  int lr = lane & 15, g = lane >> 4;
  int rx = 8 * (lr & 7);

  // staging geometry: lane -> (rsub, chunk); source pre-swizzled
  int rsub = lane >> 3, cch = lane & 7;
  int csw = 8 * (cch ^ rsub);
  const unsigned short* Asrc =
      Ahi + (size_t)(bm*256 + wmh*128 + wq*32 + rsub)*DM + csw;
  const unsigned short* Bsrc =
      Bhi + (size_t)(bn*256 + wq*64 + wmh*32 + rsub)*DM + csw;

  f32x4 acc[8][4];
  #pragma unroll
  for (int i = 0; i < 8; ++i)
    #pragma unroll
    for (int j = 0; j < 4; ++j) acc[i][j] = (f32x4){0.f, 0.f, 0.f, 0.f};

  bf16x8 a_frag[8];   // mi(4) x ks(2) for current half
  bf16x8 b_frag[4];   // nj(2) x ks(2) for current v

#define PH_READS_A(h)                                                      \
  _Pragma("unroll") for (int m = 0; m < 4; ++m)                            \
    _Pragma("unroll") for (int ks = 0; ks < 2; ++ks)                       \
      a_frag[m*2+ks] = *(const bf16x8*)                                    \
          &A_lds[buf][wmh*128 + ((h)*4+m)*16 + lr][(ks*32 + 8*g) ^ rx];

#define PH_READS_B(v)                                                      \
  _Pragma("unroll") for (int n = 0; n < 2; ++n)                            \
    _Pragma("unroll") for (int ks = 0; ks < 2; ++ks)                       \
      b_frag[n*2+ks] = *(const bf16x8*)                                    \
          &B_lds[buf][wq*64 + ((v)*2+n)*16 + lr][(ks*32 + 8*g) ^ rx];

#define PH_MFMA(h, v)                                                      \
  __builtin_amdgcn_s_setprio(1);                                           \
  _Pragma("unroll") for (int m = 0; m < 4; ++m)                            \
    _Pragma("unroll") for (int n = 0; n < 2; ++n)                          \
      _Pragma("unroll") for (int ks = 0; ks < 2; ++ks)                     \
        acc[(h)*4+m][(v)*2+n] = __builtin_amdgcn_mfma_f32_16x16x32_bf16(   \
            a_frag[m*2+ks], b_frag[n*2+ks], acc[(h)*4+m][(v)*2+n], 0,0,0); \
  __builtin_amdgcn_s_setprio(0);

  // prologue: stage tile 0 into buf 0 (8 x 1KB per wave, own shares)
  {
    unsigned short* Ad = &A_lds[0][wmh*128 + wq*32][0];
    unsigned short* Bd = &B_lds[0][wq*64 + wmh*32][0];
    #pragma unroll
    for (int j = 0; j < 4; ++j) {
      gl16(Asrc + (size_t)j*8*DM, Ad + j*8*64);
      gl16(Bsrc + (size_t)j*8*DM, Bd + j*8*64);
    }
  }

  #pragma unroll 1
  for (int kt = 0; kt < 16; ++kt) {
    int buf = kt & 1;
    const unsigned short* An = Asrc + (kt+1)*64;
    const unsigned short* Bn = Bsrc + (kt+1)*64;
    unsigned short* Ad = &A_lds[buf^1][wmh*128 + wq*32][0];
    unsigned short* Bd = &B_lds[buf^1][wq*64 + wmh*32][0];
    bool pf = kt < 15;

    // ---- phase 0: quadrant (0,0); stage A j0,j1; tile-boundary wait ----
    if (pf) { gl16(An, Ad); gl16(An + (size_t)8*DM, Ad + 8*64); }
    if (pf) asm volatile("s_waitcnt vmcnt(2)" ::: "memory");
    else    asm volatile("s_waitcnt vmcnt(0)" ::: "memory");
    __builtin_amdgcn_sched_barrier(0);
    __builtin_amdgcn_s_barrier();
    PH_READS_A(0)
    PH_READS_B(0)
    __builtin_amdgcn_s_barrier();
    PH_MFMA(0, 0)
    __builtin_amdgcn_s_barrier();

    // ---- phase 1: quadrant (0,1); stage A j2,j3 ----
    if (pf) { gl16(An + (size_t)16*DM, Ad + 16*64); gl16(An + (size_t)24*DM, Ad + 24*64); }
    PH_READS_B(1)
    __builtin_amdgcn_s_barrier();
    PH_MFMA(0, 1)
    __builtin_amdgcn_s_barrier();

    // ---- phase 2: quadrant (1,0); stage B j0,j1 ----
    if (pf) { gl16(Bn, Bd); gl16(Bn + (size_t)8*DM, Bd + 8*64); }
    PH_READS_A(1)
    PH_READS_B(0)
    __builtin_amdgcn_s_barrier();
    PH_MFMA(1, 0)
    __builtin_amdgcn_s_barrier();

    // ---- phase 3: quadrant (1,1); stage B j2,j3 ----
    if (pf) { gl16(Bn + (size_t)16*DM, Bd + 16*64); gl16(Bn + (size_t)24*DM, Bd + 24*64); }
    PH_READS_B(1)
    __builtin_amdgcn_s_barrier();
    PH_MFMA(1, 1)
    __builtin_amdgcn_s_barrier();
  }

  // epilogue: C/D layout col=lane&15, row=(lane>>4)*4+reg  [m89]
  int orow0 = bm*256 + wmh*128;
  int ocol0 = bn*256 + wq*64;
  const float* bb = basev + (size_t)(bm >> 2)*DM;   // 256-row tile: single batch
  float usv[4], cv[4];
  #pragma unroll
  for (int nj = 0; nj < 4; ++nj) {
    int col = ocol0 + nj*16 + lr;
    usv[nj] = u_s[col];
    cv[nj]  = bb[col] + u_c[col] + mixer_b[col];
  }
  int rbase = g * 4;
  #pragma unroll
  for (int mi = 0; mi < 8; ++mi) {
    #pragma unroll
    for (int r = 0; r < 4; ++r) {
      int row = orow0 + mi*16 + rbase + r;
      float sim = simv[row];
      #pragma unroll
      for (int nj = 0; nj < 4; ++nj) {
        float v = acc[mi][nj][r] + sim*usv[nj] + cv[nj];
        out[(size_t)row*DM + ocol0 + nj*16 + lr] = fmaxf(v, 0.f);
      }
    }
  }
#undef PH_READS_A
#undef PH_READS_B
#undef PH_MFMA
}

extern "C" void kernel_launch(void* const* d_in, const int* in_sizes, int n_in,
                              void* d_out, int out_size, void* d_ws, size_t ws_size,
                              hipStream_t stream) {
  const float* video   = (const float*)d_in[0];
  const float* query   = (const float*)d_in[1];
  const float* vmask   = (const float*)d_in[2];
  const float* qmask   = (const float*)d_in[3];
  const float* sim_w   = (const float*)d_in[4];
  const float* cor_v_w = (const float*)d_in[5];
  const float* cor_q_w = (const float*)d_in[6];
  const float* pool_w  = (const float*)d_in[7];
  const float* mixer_w = (const float*)d_in[8];
  const float* mixer_b = (const float*)d_in[9];
  float* out = (float*)d_out;

  float* fws       = (float*)d_ws;
  float* sentence  = fws;                    // 16384
  float* u_s       = sentence + 16384;       // 1024
  float* u_c       = u_s + 1024;             // 1024
  float* basev     = u_c + 1024;             // 16384
  float* simv      = basev + 16384;          // 16384
  float* alpha_raw = simv + 16384;           // 1024
  float* psq       = alpha_raw + 1024;       // 128 (+pad to keep 16B align)
  float* partial   = psq + 128;              // 32*18*1024 = 589824
  unsigned short* Ahi = (unsigned short*)(partial + 589824);  // 16M elems (32MB)
  unsigned short* Bhi = Ahi + (size_t)MM*DM;                  // 1M elems (2MB)

  k_alpha<<<dim3(256), dim3(256), 0, stream>>>(query, pool_w, alpha_raw);
  k_sentence2<<<dim3(16, 8), dim3(256), 0, stream>>>(query, qmask, alpha_raw,
                                                     sentence, psq);
  k_conv<<<dim3(4352), dim3(256), 0, stream>>>(video, sentence, psq, vmask,
                                               mixer_w, Ahi, Bhi, simv);
  k_gemvs<<<dim3(32, 8), dim3(256), 0, stream>>>(mixer_w, sentence, sim_w,
                                                 cor_v_w, cor_q_w, partial);
  k_reduce<<<dim3(72), dim3(256), 0, stream>>>(partial, basev, u_s, u_c);
  k_gemm<<<dim3(256), dim3(512), 0, stream>>>(Ahi, Bhi, simv, u_s, u_c,
                                              basev, mixer_b, out);
}